// Round 10
// baseline (73.283 us; speedup 1.0000x reference)
//
#include <hip/hip_runtime.h>
#include <hip/hip_fp16.h>

#define D_  160
#define H_  192
#define W_  224
#define HW_ (H_ * W_)           // 43008
#define HW2_ (HW_ / 2)          // 21504
#define N_  (D_ * H_ * W_)      // 6881280
#define INV729 (1.0f / 729.0f)
#define HSEG 24
#define NSEG (H_ / HSEG)        // 8
#define NROW (HSEG + 9)         // 33 rows pushed per strip
#define UPD  (NSEG * 2)         // wave-units per d (2 half-rows)

// Intermediate: bufA = uint4 per 2 points (c0..c3 pt0, c0..c3 pt1, fp16)
//               bufB = dword per 2 points (c4 pt0, c4 pt1, fp16)

// ---------------------------------------------------------------------------
__global__ void k_init(double* acc) { *acc = 0.0; }

__device__ __forceinline__ unsigned pack2(float a, float b) {
    const __half2 h = __floats2half2_rn(a, b);
    return *(const unsigned*)&h;
}

// ---------------------------------------------------------------------------
// Fused W+H box-sum — WAVE-AUTONOMOUS, barrier-free, LDS-free.
// Each wave owns (d, h-strip, half-row of 112 w). Lane loads one float2/row
// per array; the 10-float window comes from __shfl_down of neighbor lanes.
// 2 w-points per lane, fp32 mod-9 H-ring (statically indexed, full unroll).
__global__ __launch_bounds__(256) void k_passWH(const float* __restrict__ pred,
                                                const float* __restrict__ targ,
                                                uint4* __restrict__ outA,      // [N/2]
                                                unsigned* __restrict__ outB) { // [N/2]
    const int unit = blockIdx.x * 4 + (threadIdx.x >> 6);
    const int lane = threadIdx.x & 63;
    const int d    = unit / UPD;
    const int rem  = unit % UPD;
    const int half = rem & 1;
    const int h0   = (rem >> 1) * HSEG;
    const long dbase = (long)d * HW_;
    const int wbase = half * 112;            // first output w of this half

    // load role: lane loads float2 at w = wbase-4+2*lane (fully in or out)
    const int  wld  = wbase - 4 + 2 * lane;
    const bool ldok = (lane < 60) && (wld >= 0) && (wld + 1 < W_);
    const float* pI = targ + dbase + wld;    // Ii = target
    const float* pJ = pred + dbase + wld;    // Ji = pred
    const bool cmp = (lane < 56);            // owns w0 = wbase + 2*lane

    float2 q[5][9];
    #pragma unroll
    for (int c = 0; c < 5; ++c)
        #pragma unroll
        for (int k = 0; k < 9; ++k) q[c][k] = make_float2(0.f, 0.f);
    float S0[5] = {0,0,0,0,0}, S1[5] = {0,0,0,0,0};

    // current-row regs + 1-row prefetch (latency hides under compute)
    float2 cI = make_float2(0.f, 0.f), cJ = cI, nI, nJ;
    {
        const int hh = h0 - 5;
        if (ldok && hh >= 0) {
            cI = *(const float2*)(pI + (long)hh * W_);
            cJ = *(const float2*)(pJ + (long)hh * W_);
        }
    }

    #pragma unroll
    for (int p = 0; p < NROW; ++p) {         // pushes row hh = h0-5+p
        nI = make_float2(0.f, 0.f); nJ = nI;
        {
            const int hh = h0 - 4 + p;
            if (ldok && (p + 1 < NROW) && hh >= 0 && hh < H_) {
                nI = *(const float2*)(pI + (long)hh * W_);
                nJ = *(const float2*)(pJ + (long)hh * W_);
            }
        }

        // window a[kk] = I at w0-4+kk (lane+j holds w0-4+2j), same for b/J
        float a[10], b[10];
        a[0] = cI.x; a[1] = cI.y; b[0] = cJ.x; b[1] = cJ.y;
        #pragma unroll
        for (int j = 1; j <= 4; ++j) {
            a[2*j]   = __shfl_down(cI.x, j);
            a[2*j+1] = __shfl_down(cI.y, j);
            b[2*j]   = __shfl_down(cJ.x, j);
            b[2*j+1] = __shfl_down(cJ.y, j);
        }

        float sI = 0.f, sJ = 0.f, sII = 0.f, sJJ = 0.f, sIJ = 0.f;
        #pragma unroll
        for (int kk = 0; kk < 9; ++kk) {
            sI  += a[kk];          sJ  += b[kk];
            sII += a[kk] * a[kk];  sJJ += b[kk] * b[kk];
            sIJ += a[kk] * b[kk];
        }
        float w0[5], w1[5];
        w0[0] = sI;  w1[0] = sI  + a[9] - a[0];
        w0[1] = sJ;  w1[1] = sJ  + b[9] - b[0];
        w0[2] = sII; w1[2] = sII + a[9]*a[9] - a[0]*a[0];
        w0[3] = sJJ; w1[3] = sJJ + b[9]*b[9] - b[0]*b[0];
        w0[4] = sIJ; w1[4] = sIJ + a[9]*b[9] - a[0]*b[0];

        const int ph = p % 9;                // compile-time (full unroll)
        #pragma unroll
        for (int c = 0; c < 5; ++c) {
            S0[c] += w0[c] - q[c][ph].x;
            S1[c] += w1[c] - q[c][ph].y;
            q[c][ph].x = w0[c];
            q[c][ph].y = w1[c];
        }
        if (p >= 9 && cmp) {                 // emit row h0+p-9
            const long rb = dbase + (long)(h0 + p - 9) * W_;   // even
            uint4 oA;
            oA.x = pack2(S0[0], S0[1]); oA.y = pack2(S0[2], S0[3]);
            oA.z = pack2(S1[0], S1[1]); oA.w = pack2(S1[2], S1[3]);
            outA[rb / 2 + half * 56 + lane] = oA;
            outB[rb / 2 + half * 56 + lane] = pack2(S0[4], S1[4]);
        }
        cI = nI; cJ = nJ;
    }
}

// ---------------------------------------------------------------------------
// D-axis 9-tap sliding sum + cc + reduction. TWO points per thread: one b128
// (bufA) + one b32 (bufB) per d-step. (unchanged from R9)
__global__ __launch_bounds__(256) void k_passD(const uint4* __restrict__ bufA,
                                               const unsigned* __restrict__ bufB,
                                               double* __restrict__ acc) {
    const int DSEG = D_ / 8;                // 20
    const int p2 = blockIdx.x * blockDim.x + threadIdx.x;   // < HW2_
    const int d0 = blockIdx.y * DSEG;

    float2 q[5][9], S[5];                   // .x = pt0, .y = pt1
    #pragma unroll
    for (int c = 0; c < 5; ++c) S[c] = make_float2(0.f, 0.f);

    #pragma unroll
    for (int k = 0; k < 9; ++k) {
        const int dd = d0 - 5 + k;          // d0+3 <= 143 < 160
        uint4 va = make_uint4(0u, 0u, 0u, 0u);
        unsigned vb = 0u;
        if (dd >= 0) {
            va = bufA[(long)dd * HW2_ + p2];
            vb = bufB[(long)dd * HW2_ + p2];
        }
        const float2 a01 = __half22float2(*(const __half2*)&va.x);
        const float2 a23 = __half22float2(*(const __half2*)&va.y);
        const float2 b01 = __half22float2(*(const __half2*)&va.z);
        const float2 b23 = __half22float2(*(const __half2*)&va.w);
        const float2 c44 = __half22float2(*(const __half2*)&vb);
        q[0][k] = make_float2(a01.x, b01.x); S[0].x += a01.x; S[0].y += b01.x;
        q[1][k] = make_float2(a01.y, b01.y); S[1].x += a01.y; S[1].y += b01.y;
        q[2][k] = make_float2(a23.x, b23.x); S[2].x += a23.x; S[2].y += b23.x;
        q[3][k] = make_float2(a23.y, b23.y); S[3].x += a23.y; S[3].y += b23.y;
        q[4][k] = make_float2(c44.x, c44.y); S[4].x += c44.x; S[4].y += c44.y;
    }

    float myacc = 0.f;
    #pragma unroll
    for (int j = 0; j < DSEG; ++j) {        // output d = d0+j
        const int dd = d0 + 4 + j;
        uint4 va = make_uint4(0u, 0u, 0u, 0u);
        unsigned vb = 0u;
        if (dd < D_) {
            va = bufA[(long)dd * HW2_ + p2];
            vb = bufB[(long)dd * HW2_ + p2];
        }
        const float2 a01 = __half22float2(*(const __half2*)&va.x);
        const float2 a23 = __half22float2(*(const __half2*)&va.y);
        const float2 b01 = __half22float2(*(const __half2*)&va.z);
        const float2 b23 = __half22float2(*(const __half2*)&va.w);
        const float2 c44 = __half22float2(*(const __half2*)&vb);
        const float2 nv[5] = {
            make_float2(a01.x, b01.x), make_float2(a01.y, b01.y),
            make_float2(a23.x, b23.x), make_float2(a23.y, b23.y),
            make_float2(c44.x, c44.y)
        };
        const int ph = j % 9;               // compile-time
        #pragma unroll
        for (int c = 0; c < 5; ++c) {
            S[c].x += nv[c].x - q[c][ph].x;
            S[c].y += nv[c].y - q[c][ph].y;
            q[c][ph] = nv[c];
        }
        #pragma unroll
        for (int e = 0; e < 2; ++e) {
            const float mu1 = (e ? S[0].y : S[0].x) * INV729;
            const float mu2 = (e ? S[1].y : S[1].x) * INV729;
            const float s1  = (e ? S[2].y : S[2].x) * INV729 - mu1 * mu1;
            const float s2  = (e ? S[3].y : S[3].x) * INV729 - mu2 * mu2;
            const float s12 = (e ? S[4].y : S[4].x) * INV729 - mu1 * mu2;
            const float den = fmaxf(s1 * s2, 1.1920929e-7f);  // finfo(f32).eps
            myacc += (s12 * s12) / den;
        }
    }

    __shared__ float red[256];
    red[threadIdx.x] = myacc;
    __syncthreads();
    #pragma unroll
    for (int s = 128; s > 0; s >>= 1) {
        if (threadIdx.x < s) red[threadIdx.x] += red[threadIdx.x + s];
        __syncthreads();
    }
    if (threadIdx.x == 0) atomicAdd(acc, (double)red[0]);
}

// ---------------------------------------------------------------------------
__global__ void k_fin(const double* __restrict__ acc, float* __restrict__ out) {
    out[0] = (float)(-(*acc) / (double)N_);
}

// ---------------------------------------------------------------------------
extern "C" void kernel_launch(void* const* d_in, const int* in_sizes, int n_in,
                              void* d_out, int out_size, void* d_ws, size_t ws_size,
                              hipStream_t stream) {
    const float* pred = (const float*)d_in[0];
    const float* targ = (const float*)d_in[1];

    uint4*    bufA = (uint4*)d_ws;                                 // N/2 x 16B
    unsigned* bufB = (unsigned*)((char*)d_ws + (size_t)(N_ / 2) * 16);  // N/2 x 4B
    double*   acc  = (double*)((char*)d_ws + (size_t)(N_ / 2) * 16 + (size_t)(N_ / 2) * 4);
    float*    out  = (float*)d_out;

    k_init<<<1, 1, 0, stream>>>(acc);
    // 2560 wave-units (160 d x 8 hseg x 2 halves), 4 waves/block -> 640 blocks
    k_passWH<<<D_ * UPD / 4, 256, 0, stream>>>(pred, targ, bufA, bufB);
    dim3 g3(HW2_ / 256, 8);     // 84 x 8 = 672 blocks
    k_passD<<<g3, 256, 0, stream>>>(bufA, bufB, acc);
    k_fin<<<1, 1, 0, stream>>>(acc, out);
}

// Round 11
// 61.332 us; speedup vs baseline: 1.1949x; 1.1949x over previous
//
#include <hip/hip_runtime.h>
#include <hip/hip_fp16.h>

#define D_  160
#define H_  192
#define W_  224
#define HW_ (H_ * W_)           // 43008
#define HW2_ (HW_ / 2)          // 21504
#define N_  (D_ * H_ * W_)      // 6881280
#define INV729 (1.0f / 729.0f)
#define HSEG 16
#define NSEG (H_ / HSEG)        // 12
#define NROW (HSEG + 9)         // 25 rows pushed per strip
#define UPD  (NSEG * 2)         // wave-units per d (2 half-rows) = 24

// Intermediate: bufA = uint4 per 2 points (c0..c3 pt0, c0..c3 pt1, fp16)
//               bufB = dword per 2 points (c4 pt0, c4 pt1, fp16)

// ---------------------------------------------------------------------------
__global__ void k_init(double* acc) { *acc = 0.0; }

__device__ __forceinline__ unsigned pack2(float a, float b) {
    const __half2 h = __floats2half2_rn(a, b);
    return *(const unsigned*)&h;
}

// ---------------------------------------------------------------------------
// Fused W+H box-sum — wave-autonomous with WAVE-PRIVATE LDS staging.
// No __syncthreads anywhere: each wave stages its own rows into its own LDS
// slice (same-wave DS ops are FIFO-ordered; compiler inserts lgkmcnt).
// Pipelining: step p writes row p+1 into buf[cur^1], reads row p from
// buf[cur] (written last step); global loads run 2 rows ahead (pfE/pfO).
__global__ __launch_bounds__(256) void k_passWH(const float* __restrict__ pred,
                                                const float* __restrict__ targ,
                                                uint4* __restrict__ outA,      // [N/2]
                                                unsigned* __restrict__ outB) { // [N/2]
    __shared__ __attribute__((aligned(16))) float lds[4][2][2][128]; // [wave][buf][arr][slot]
    const int wid  = threadIdx.x >> 6;
    const int lane = threadIdx.x & 63;
    const int unit = blockIdx.x * 4 + wid;
    const int d    = unit / UPD;
    const int rem  = unit % UPD;
    const int half = rem & 1;
    const int h0   = (rem >> 1) * HSEG;
    const long dbase = (long)d * HW_;
    const int wbase = half * 112;            // first output w of this half

    // staging role: lanes 0-29 stage I (targ), 30-59 stage J (pred), 4 floats each
    const bool isld = (lane < 60);
    const int  arr  = (lane >= 30) ? 1 : 0;
    const int  j    = arr ? lane - 30 : lane;          // chunk 0..29
    const int  ws   = wbase - 4 + 4 * j;               // chunk w-start
    const bool ldok = isld && (ws >= 0) && (ws + 3 < W_);  // edge chunks -> zeros
    const float* gsrc = (arr ? pred : targ) + dbase + ws;

    // fp32 H-ring: q[c][p%9] = (w-sum pt0, pt1) of push-index p
    float2 q[5][9];
    #pragma unroll
    for (int c = 0; c < 5; ++c)
        #pragma unroll
        for (int k = 0; k < 9; ++k) q[c][k] = make_float2(0.f, 0.f);
    float S0[5] = {0,0,0,0,0}, S1[5] = {0,0,0,0,0};

    auto fetch = [&](int p) -> float4 {
        float4 f = make_float4(0.f, 0.f, 0.f, 0.f);
        const int hh = h0 - 5 + p;
        if (ldok && hh >= 0 && hh < H_)
            f = *(const float4*)(gsrc + (long)hh * W_);
        return f;
    };

    float4 pfE = fetch(0);                   // even-parity row in flight
    float4 pfO = fetch(1);                   // odd-parity row in flight
    // prologue: write row 0 into buf0
    if (isld) *(float4*)&lds[wid][0][arr][4 * j] = pfE;
    pfE = fetch(2);

    #pragma unroll
    for (int p = 0; p < NROW; ++p) {
        const int cur = p & 1;
        // write row p+1 (parity cur^1) into buf[cur^1]
        if (isld) *(float4*)&lds[wid][cur ^ 1][arr][4 * j] = (cur ? pfE : pfO);
        // refill the just-consumed parity reg with row p+3
        if (cur) pfE = fetch(p + 3);
        else     pfO = fetch(p + 3);

        // read row p from buf[cur] (written last step -> latency already hidden)
        if (lane < 56) {
            float a[10], b[10];
            #pragma unroll
            for (int m = 0; m < 5; ++m) {
                const float2 va = *(const float2*)&lds[wid][cur][0][2 * lane + 2 * m];
                const float2 vb = *(const float2*)&lds[wid][cur][1][2 * lane + 2 * m];
                a[2*m] = va.x; a[2*m+1] = va.y;
                b[2*m] = vb.x; b[2*m+1] = vb.y;
            }
            float sI = 0.f, sJ = 0.f, sII = 0.f, sJJ = 0.f, sIJ = 0.f;
            #pragma unroll
            for (int kk = 0; kk < 9; ++kk) {
                sI  += a[kk];          sJ  += b[kk];
                sII += a[kk] * a[kk];  sJJ += b[kk] * b[kk];
                sIJ += a[kk] * b[kk];
            }
            float w0[5], w1[5];
            w0[0] = sI;  w1[0] = sI  + a[9] - a[0];
            w0[1] = sJ;  w1[1] = sJ  + b[9] - b[0];
            w0[2] = sII; w1[2] = sII + a[9]*a[9] - a[0]*a[0];
            w0[3] = sJJ; w1[3] = sJJ + b[9]*b[9] - b[0]*b[0];
            w0[4] = sIJ; w1[4] = sIJ + a[9]*b[9] - a[0]*b[0];

            const int ph = p % 9;            // compile-time (full unroll)
            #pragma unroll
            for (int c = 0; c < 5; ++c) {
                S0[c] += w0[c] - q[c][ph].x;
                S1[c] += w1[c] - q[c][ph].y;
                q[c][ph].x = w0[c];
                q[c][ph].y = w1[c];
            }
            if (p >= 9) {                    // emit row h0+p-9
                const long rb = dbase + (long)(h0 + p - 9) * W_;  // even
                uint4 oA;
                oA.x = pack2(S0[0], S0[1]); oA.y = pack2(S0[2], S0[3]);
                oA.z = pack2(S1[0], S1[1]); oA.w = pack2(S1[2], S1[3]);
                outA[rb / 2 + half * 56 + lane] = oA;
                outB[rb / 2 + half * 56 + lane] = pack2(S0[4], S1[4]);
            }
        }
    }
}

// ---------------------------------------------------------------------------
// D-axis 9-tap sliding sum + cc + reduction. TWO points per thread: one b128
// (bufA) + one b32 (bufB) per d-step. (unchanged from R9 — proven)
__global__ __launch_bounds__(256) void k_passD(const uint4* __restrict__ bufA,
                                               const unsigned* __restrict__ bufB,
                                               double* __restrict__ acc) {
    const int DSEG = D_ / 8;                // 20
    const int p2 = blockIdx.x * blockDim.x + threadIdx.x;   // < HW2_
    const int d0 = blockIdx.y * DSEG;

    float2 q[5][9], S[5];                   // .x = pt0, .y = pt1
    #pragma unroll
    for (int c = 0; c < 5; ++c) S[c] = make_float2(0.f, 0.f);

    #pragma unroll
    for (int k = 0; k < 9; ++k) {
        const int dd = d0 - 5 + k;          // d0+3 <= 153 < 160
        uint4 va = make_uint4(0u, 0u, 0u, 0u);
        unsigned vb = 0u;
        if (dd >= 0) {
            va = bufA[(long)dd * HW2_ + p2];
            vb = bufB[(long)dd * HW2_ + p2];
        }
        const float2 a01 = __half22float2(*(const __half2*)&va.x);
        const float2 a23 = __half22float2(*(const __half2*)&va.y);
        const float2 b01 = __half22float2(*(const __half2*)&va.z);
        const float2 b23 = __half22float2(*(const __half2*)&va.w);
        const float2 c44 = __half22float2(*(const __half2*)&vb);
        q[0][k] = make_float2(a01.x, b01.x); S[0].x += a01.x; S[0].y += b01.x;
        q[1][k] = make_float2(a01.y, b01.y); S[1].x += a01.y; S[1].y += b01.y;
        q[2][k] = make_float2(a23.x, b23.x); S[2].x += a23.x; S[2].y += b23.x;
        q[3][k] = make_float2(a23.y, b23.y); S[3].x += a23.y; S[3].y += b23.y;
        q[4][k] = make_float2(c44.x, c44.y); S[4].x += c44.x; S[4].y += c44.y;
    }

    float myacc = 0.f;
    #pragma unroll
    for (int j = 0; j < DSEG; ++j) {        // output d = d0+j
        const int dd = d0 + 4 + j;
        uint4 va = make_uint4(0u, 0u, 0u, 0u);
        unsigned vb = 0u;
        if (dd < D_) {
            va = bufA[(long)dd * HW2_ + p2];
            vb = bufB[(long)dd * HW2_ + p2];
        }
        const float2 a01 = __half22float2(*(const __half2*)&va.x);
        const float2 a23 = __half22float2(*(const __half2*)&va.y);
        const float2 b01 = __half22float2(*(const __half2*)&va.z);
        const float2 b23 = __half22float2(*(const __half2*)&va.w);
        const float2 c44 = __half22float2(*(const __half2*)&vb);
        const float2 nv[5] = {
            make_float2(a01.x, b01.x), make_float2(a01.y, b01.y),
            make_float2(a23.x, b23.x), make_float2(a23.y, b23.y),
            make_float2(c44.x, c44.y)
        };
        const int ph = j % 9;               // compile-time
        #pragma unroll
        for (int c = 0; c < 5; ++c) {
            S[c].x += nv[c].x - q[c][ph].x;
            S[c].y += nv[c].y - q[c][ph].y;
            q[c][ph] = nv[c];
        }
        #pragma unroll
        for (int e = 0; e < 2; ++e) {
            const float mu1 = (e ? S[0].y : S[0].x) * INV729;
            const float mu2 = (e ? S[1].y : S[1].x) * INV729;
            const float s1  = (e ? S[2].y : S[2].x) * INV729 - mu1 * mu1;
            const float s2  = (e ? S[3].y : S[3].x) * INV729 - mu2 * mu2;
            const float s12 = (e ? S[4].y : S[4].x) * INV729 - mu1 * mu2;
            const float den = fmaxf(s1 * s2, 1.1920929e-7f);  // finfo(f32).eps
            myacc += (s12 * s12) / den;
        }
    }

    __shared__ float red[256];
    red[threadIdx.x] = myacc;
    __syncthreads();
    #pragma unroll
    for (int s = 128; s > 0; s >>= 1) {
        if (threadIdx.x < s) red[threadIdx.x] += red[threadIdx.x + s];
        __syncthreads();
    }
    if (threadIdx.x == 0) atomicAdd(acc, (double)red[0]);
}

// ---------------------------------------------------------------------------
__global__ void k_fin(const double* __restrict__ acc, float* __restrict__ out) {
    out[0] = (float)(-(*acc) / (double)N_);
}

// ---------------------------------------------------------------------------
extern "C" void kernel_launch(void* const* d_in, const int* in_sizes, int n_in,
                              void* d_out, int out_size, void* d_ws, size_t ws_size,
                              hipStream_t stream) {
    const float* pred = (const float*)d_in[0];
    const float* targ = (const float*)d_in[1];

    uint4*    bufA = (uint4*)d_ws;                                 // N/2 x 16B
    unsigned* bufB = (unsigned*)((char*)d_ws + (size_t)(N_ / 2) * 16);  // N/2 x 4B
    double*   acc  = (double*)((char*)d_ws + (size_t)(N_ / 2) * 16 + (size_t)(N_ / 2) * 4);
    float*    out  = (float*)d_out;

    k_init<<<1, 1, 0, stream>>>(acc);
    // 3840 wave-units (160 d x 12 hseg x 2 halves), 4 waves/block -> 960 blocks
    k_passWH<<<D_ * UPD / 4, 256, 0, stream>>>(pred, targ, bufA, bufB);
    dim3 g3(HW2_ / 256, 8);     // 84 x 8 = 672 blocks
    k_passD<<<g3, 256, 0, stream>>>(bufA, bufB, acc);
    k_fin<<<1, 1, 0, stream>>>(acc, out);
}

// Round 12
// 56.488 us; speedup vs baseline: 1.2973x; 1.0858x over previous
//
#include <hip/hip_runtime.h>
#include <hip/hip_fp16.h>

#define D_  160
#define H_  192
#define W_  224
#define HW_ (H_ * W_)           // 43008
#define HW2_ (HW_ / 2)          // 21504
#define N_  (D_ * H_ * W_)      // 6881280
#define INV729 (1.0f / 729.0f)
#define HSEG 12
#define NSEG (H_ / HSEG)        // 16
#define NROW (HSEG + 9)         // 21 rows pushed per strip
#define UPD  (NSEG * 2)         // wave-units per d (2 half-rows) = 32

// Intermediate: bufA = uint4 per 2 points (c0..c3 pt0, c0..c3 pt1, fp16)
//               bufB = dword per 2 points (c4 pt0, c4 pt1, fp16)

__device__ __forceinline__ unsigned pack2(float a, float b) {
    const __half2 h = __floats2half2_rn(a, b);
    return *(const unsigned*)&h;
}

// ---------------------------------------------------------------------------
// Fused W+H box-sum — wave-autonomous, wave-private LDS, 4-deep static
// prefetch pipeline, unconditional clamped global loads (zero via cndmask).
__global__ __launch_bounds__(256) void k_passWH(const float* __restrict__ pred,
                                                const float* __restrict__ targ,
                                                uint4* __restrict__ outA,      // [N/2]
                                                unsigned* __restrict__ outB,   // [N/2]
                                                double* __restrict__ acc) {
    __shared__ __attribute__((aligned(16))) float lds[4][2][2][128]; // [wave][buf][arr][slot]
    if (blockIdx.x == 0 && threadIdx.x == 0) *acc = 0.0;  // runs before k_passD (stream order)

    const int wid  = threadIdx.x >> 6;
    const int lane = threadIdx.x & 63;
    const int unit = blockIdx.x * 4 + wid;
    const int d    = unit / UPD;
    const int rem  = unit % UPD;
    const int half = rem & 1;
    const int h0   = (rem >> 1) * HSEG;
    const long dbase = (long)d * HW_;
    const int wbase = half * 112;            // first output w of this half

    // staging role: lanes 0-29 stage I (targ), 30-59 stage J (pred), 4 floats each
    const bool isld = (lane < 60);
    const int  arr  = (lane >= 30) ? 1 : 0;
    const int  jj   = arr ? lane - 30 : lane;          // chunk 0..29 (junk for 60-63)
    const int  ws   = wbase - 4 + 4 * jj;              // chunk w-start
    const bool geom = isld && (ws >= 0) && (ws + 3 < W_);   // halo chunks stay zero
    const int  wsc  = ws < 0 ? 0 : (ws > W_ - 4 ? W_ - 4 : ws);  // safe address
    const float* gsrc = (arr ? pred : targ) + dbase + wsc;

    // fp32 H-ring
    float2 q[5][9];
    #pragma unroll
    for (int c = 0; c < 5; ++c)
        #pragma unroll
        for (int k = 0; k < 9; ++k) q[c][k] = make_float2(0.f, 0.f);
    float S0[5] = {0,0,0,0,0}, S1[5] = {0,0,0,0,0};

    // unconditional clamped fetch of push-row p (row hh = h0-5+p)
    auto fetch = [&](int p) -> float4 {
        const int hh = h0 - 5 + p;
        const int hc = hh < 0 ? 0 : (hh >= H_ ? H_ - 1 : hh);
        float4 f = *(const float4*)(gsrc + (long)hc * W_);
        if (!(geom && hh >= 0 && hh < H_)) f = make_float4(0.f, 0.f, 0.f, 0.f);
        return f;
    };

    // prologue: fill 4-slot pipeline, write row 0, refill slot 0
    float4 pf[4];
    pf[0] = fetch(0); pf[1] = fetch(1); pf[2] = fetch(2); pf[3] = fetch(3);
    if (isld) *(float4*)&lds[wid][0][arr][4 * jj] = pf[0];
    pf[0] = fetch(4);

    #pragma unroll
    for (int p = 0; p < NROW; ++p) {
        // write row p+1 (slot (p+1)%4, loaded 4 steps ago) into buf[(p+1)%2]
        if (isld) *(float4*)&lds[wid][(p + 1) & 1][arr][4 * jj] = pf[(p + 1) & 3];
        pf[(p + 1) & 3] = fetch(p + 5);      // refill: 4 loads stay in flight
        // hazard: same-wave DS FIFO -> step p-1's reads of buf[(p+1)&1]
        // precede this write in program order. No barriers needed.

        if (lane < 56) {                     // compute row p from buf[p&1]
            float a[10], b[10];
            #pragma unroll
            for (int m = 0; m < 5; ++m) {
                const float2 va = *(const float2*)&lds[wid][p & 1][0][2 * lane + 2 * m];
                const float2 vb = *(const float2*)&lds[wid][p & 1][1][2 * lane + 2 * m];
                a[2*m] = va.x; a[2*m+1] = va.y;
                b[2*m] = vb.x; b[2*m+1] = vb.y;
            }
            float sI = 0.f, sJ = 0.f, sII = 0.f, sJJ = 0.f, sIJ = 0.f;
            #pragma unroll
            for (int kk = 0; kk < 9; ++kk) {
                sI  += a[kk];          sJ  += b[kk];
                sII += a[kk] * a[kk];  sJJ += b[kk] * b[kk];
                sIJ += a[kk] * b[kk];
            }
            float w0[5], w1[5];
            w0[0] = sI;  w1[0] = sI  + a[9] - a[0];
            w0[1] = sJ;  w1[1] = sJ  + b[9] - b[0];
            w0[2] = sII; w1[2] = sII + a[9]*a[9] - a[0]*a[0];
            w0[3] = sJJ; w1[3] = sJJ + b[9]*b[9] - b[0]*b[0];
            w0[4] = sIJ; w1[4] = sIJ + a[9]*b[9] - a[0]*b[0];

            const int ph = p % 9;            // compile-time (full unroll)
            #pragma unroll
            for (int c = 0; c < 5; ++c) {
                S0[c] += w0[c] - q[c][ph].x;
                S1[c] += w1[c] - q[c][ph].y;
                q[c][ph].x = w0[c];
                q[c][ph].y = w1[c];
            }
            if (p >= 9) {                    // emit row h0+p-9
                const long rb = dbase + (long)(h0 + p - 9) * W_;  // even
                uint4 oA;
                oA.x = pack2(S0[0], S0[1]); oA.y = pack2(S0[2], S0[3]);
                oA.z = pack2(S1[0], S1[1]); oA.w = pack2(S1[2], S1[3]);
                outA[rb / 2 + half * 56 + lane] = oA;
                outB[rb / 2 + half * 56 + lane] = pack2(S0[4], S1[4]);
            }
        }
    }
}

// ---------------------------------------------------------------------------
// D-axis 9-tap sliding sum + cc + reduction. TWO points per thread: one b128
// (bufA) + one b32 (bufB) per d-step. (unchanged — proven ~10 us)
__global__ __launch_bounds__(256) void k_passD(const uint4* __restrict__ bufA,
                                               const unsigned* __restrict__ bufB,
                                               double* __restrict__ acc) {
    const int DSEG = D_ / 8;                // 20
    const int p2 = blockIdx.x * blockDim.x + threadIdx.x;   // < HW2_
    const int d0 = blockIdx.y * DSEG;

    float2 q[5][9], S[5];                   // .x = pt0, .y = pt1
    #pragma unroll
    for (int c = 0; c < 5; ++c) S[c] = make_float2(0.f, 0.f);

    #pragma unroll
    for (int k = 0; k < 9; ++k) {
        const int dd = d0 - 5 + k;          // d0+3 <= 143 < 160
        uint4 va = make_uint4(0u, 0u, 0u, 0u);
        unsigned vb = 0u;
        if (dd >= 0) {
            va = bufA[(long)dd * HW2_ + p2];
            vb = bufB[(long)dd * HW2_ + p2];
        }
        const float2 a01 = __half22float2(*(const __half2*)&va.x);
        const float2 a23 = __half22float2(*(const __half2*)&va.y);
        const float2 b01 = __half22float2(*(const __half2*)&va.z);
        const float2 b23 = __half22float2(*(const __half2*)&va.w);
        const float2 c44 = __half22float2(*(const __half2*)&vb);
        q[0][k] = make_float2(a01.x, b01.x); S[0].x += a01.x; S[0].y += b01.x;
        q[1][k] = make_float2(a01.y, b01.y); S[1].x += a01.y; S[1].y += b01.y;
        q[2][k] = make_float2(a23.x, b23.x); S[2].x += a23.x; S[2].y += b23.x;
        q[3][k] = make_float2(a23.y, b23.y); S[3].x += a23.y; S[3].y += b23.y;
        q[4][k] = make_float2(c44.x, c44.y); S[4].x += c44.x; S[4].y += c44.y;
    }

    float myacc = 0.f;
    #pragma unroll
    for (int j = 0; j < DSEG; ++j) {        // output d = d0+j
        const int dd = d0 + 4 + j;
        uint4 va = make_uint4(0u, 0u, 0u, 0u);
        unsigned vb = 0u;
        if (dd < D_) {
            va = bufA[(long)dd * HW2_ + p2];
            vb = bufB[(long)dd * HW2_ + p2];
        }
        const float2 a01 = __half22float2(*(const __half2*)&va.x);
        const float2 a23 = __half22float2(*(const __half2*)&va.y);
        const float2 b01 = __half22float2(*(const __half2*)&va.z);
        const float2 b23 = __half22float2(*(const __half2*)&va.w);
        const float2 c44 = __half22float2(*(const __half2*)&vb);
        const float2 nv[5] = {
            make_float2(a01.x, b01.x), make_float2(a01.y, b01.y),
            make_float2(a23.x, b23.x), make_float2(a23.y, b23.y),
            make_float2(c44.x, c44.y)
        };
        const int ph = j % 9;               // compile-time
        #pragma unroll
        for (int c = 0; c < 5; ++c) {
            S[c].x += nv[c].x - q[c][ph].x;
            S[c].y += nv[c].y - q[c][ph].y;
            q[c][ph] = nv[c];
        }
        #pragma unroll
        for (int e = 0; e < 2; ++e) {
            const float mu1 = (e ? S[0].y : S[0].x) * INV729;
            const float mu2 = (e ? S[1].y : S[1].x) * INV729;
            const float s1  = (e ? S[2].y : S[2].x) * INV729 - mu1 * mu1;
            const float s2  = (e ? S[3].y : S[3].x) * INV729 - mu2 * mu2;
            const float s12 = (e ? S[4].y : S[4].x) * INV729 - mu1 * mu2;
            const float den = fmaxf(s1 * s2, 1.1920929e-7f);  // finfo(f32).eps
            myacc += (s12 * s12) / den;
        }
    }

    __shared__ float red[256];
    red[threadIdx.x] = myacc;
    __syncthreads();
    #pragma unroll
    for (int s = 128; s > 0; s >>= 1) {
        if (threadIdx.x < s) red[threadIdx.x] += red[threadIdx.x + s];
        __syncthreads();
    }
    if (threadIdx.x == 0) atomicAdd(acc, (double)red[0]);
}

// ---------------------------------------------------------------------------
__global__ void k_fin(const double* __restrict__ acc, float* __restrict__ out) {
    out[0] = (float)(-(*acc) / (double)N_);
}

// ---------------------------------------------------------------------------
extern "C" void kernel_launch(void* const* d_in, const int* in_sizes, int n_in,
                              void* d_out, int out_size, void* d_ws, size_t ws_size,
                              hipStream_t stream) {
    const float* pred = (const float*)d_in[0];
    const float* targ = (const float*)d_in[1];

    uint4*    bufA = (uint4*)d_ws;                                 // N/2 x 16B
    unsigned* bufB = (unsigned*)((char*)d_ws + (size_t)(N_ / 2) * 16);  // N/2 x 4B
    double*   acc  = (double*)((char*)d_ws + (size_t)(N_ / 2) * 16 + (size_t)(N_ / 2) * 4);
    float*    out  = (float*)d_out;

    // 5120 wave-units (160 d x 16 hseg x 2 halves), 4 waves/block -> 1280 blocks
    k_passWH<<<D_ * UPD / 4, 256, 0, stream>>>(pred, targ, bufA, bufB, acc);
    dim3 g3(HW2_ / 256, 8);     // 84 x 8 = 672 blocks
    k_passD<<<g3, 256, 0, stream>>>(bufA, bufB, acc);
    k_fin<<<1, 1, 0, stream>>>(acc, out);
}